// Round 1
// baseline (1085.222 us; speedup 1.0000x reference)
//
#include <hip/hip_runtime.h>
#include <hip/hip_bf16.h>

typedef __attribute__((ext_vector_type(4))) float f32x4;
typedef __attribute__((ext_vector_type(8))) short bf16x8;

#define B_ROWS 16384
#define IN_DIM 768
#define H1 512
#define H2 256
#define NC 50
#define NC_PAD 64
#define NE 8
#define RH1 256
#define RH2 128

static __device__ __forceinline__ f32x4 mfma16(bf16x8 a, bf16x8 b, f32x4 c) {
    return __builtin_amdgcn_mfma_f32_16x16x32_bf16(a, b, c, 0, 0, 0);
}

// ---------------- ternarize: W (E, rows, cols) f32 -> ternary {-1,0,1} bf16 (E, rows_pad, cols),
// scale (mean|W| per expert matrix) stored separately in f32.
__global__ __launch_bounds__(512) void ternarize_kernel(
    const float* __restrict__ W, __hip_bfloat16* __restrict__ Wq,
    float* __restrict__ scales, int rows, int cols, int rows_pad)
{
    const int e = blockIdx.x;
    const int n = rows * cols;
    const float* We = W + (size_t)e * n;
    __hip_bfloat16* Wo = Wq + (size_t)e * rows_pad * cols;

    float s = 0.f;
    for (int i = threadIdx.x; i < n; i += 512) s += fabsf(We[i]);
    // block reduce (8 waves)
    __shared__ float red[9];
    const int lane = threadIdx.x & 63, wave = threadIdx.x >> 6;
    #pragma unroll
    for (int o = 32; o; o >>= 1) s += __shfl_down(s, o);
    if (lane == 0) red[wave] = s;
    __syncthreads();
    if (threadIdx.x == 0) {
        float t = 0.f;
        #pragma unroll
        for (int i = 0; i < 8; ++i) t += red[i];
        red[8] = t / (float)n;
        scales[e] = red[8];
    }
    __syncthreads();

    const int ntot = rows_pad * cols;
    for (int i = threadIdx.x; i < ntot; i += 512) {
        float q = 0.f;
        if (i < n) {
            float w = We[i];
            q = (fabsf(w) > 0.05f) ? (w > 0.f ? 1.f : -1.f) : 0.f;
        }
        Wo[i] = __float2bfloat16(q);
    }
}

// ---------------- f32 GEMM:  C[M][N] = act(A[M][K] * B[N][K]^T + bias[N])
template<int DO_RELU>
__global__ __launch_bounds__(256) void gemm_nt_f32(
    const float* __restrict__ A, const float* __restrict__ Bw,
    const float* __restrict__ bias, float* __restrict__ C,
    int M, int N, int K)
{
    __shared__ float As[16][68];
    __shared__ float Bs[16][68];
    const int tid = threadIdx.x;
    const int tx = tid & 15, ty = tid >> 4;
    const int row0 = blockIdx.x * 64, col0 = blockIdx.y * 64;
    float acc[4][4] = {};
    const int kl = tid & 15, rb = tid >> 4;
    for (int kk = 0; kk < K; kk += 16) {
        #pragma unroll
        for (int it = 0; it < 4; ++it) {
            int r = rb + it * 16;
            As[kl][r] = A[(size_t)(row0 + r) * K + kk + kl];
            Bs[kl][r] = Bw[(size_t)(col0 + r) * K + kk + kl];
        }
        __syncthreads();
        #pragma unroll
        for (int k2 = 0; k2 < 16; ++k2) {
            float4 av = *(const float4*)&As[k2][ty * 4];
            float4 bv = *(const float4*)&Bs[k2][tx * 4];
            float a[4] = {av.x, av.y, av.z, av.w};
            float b[4] = {bv.x, bv.y, bv.z, bv.w};
            #pragma unroll
            for (int i = 0; i < 4; ++i)
                #pragma unroll
                for (int j = 0; j < 4; ++j)
                    acc[i][j] = fmaf(a[i], b[j], acc[i][j]);
        }
        __syncthreads();
    }
    #pragma unroll
    for (int j = 0; j < 4; ++j) {
        float bv = bias[col0 + tx * 4 + j];
        #pragma unroll
        for (int i = 0; i < 4; ++i) {
            float v = acc[i][j] + bv;
            if (DO_RELU) v = v > 0.f ? v : 0.f;
            C[(size_t)(row0 + ty * 4 + i) * N + col0 + tx * 4 + j] = v;
        }
    }
}

// ---------------- router head: logits(8) from h2(128), softmax, top-2, gate
__global__ __launch_bounds__(256) void router_head_kernel(
    const float* __restrict__ h2, const float* __restrict__ rW3,
    const float* __restrict__ rb3, float* __restrict__ router_p,
    float* __restrict__ gate, float* __restrict__ lb_out)
{
    const int wave = threadIdx.x >> 6;
    const int lane = threadIdx.x & 63;
    const int b = blockIdx.x * 4 + wave;
    const int o = lane >> 3;   // expert 0..7
    const int kq = lane & 7;   // k chunk
    const float* h = h2 + (size_t)b * RH2;
    const float* w = rW3 + o * RH2;
    float s = 0.f;
    #pragma unroll
    for (int k = 0; k < 16; ++k) s += h[kq * 16 + k] * w[kq * 16 + k];
    s += __shfl_xor(s, 1);
    s += __shfl_xor(s, 2);
    s += __shfl_xor(s, 4);
    float logit = s + rb3[o];   // all 8 lanes of group o now hold logit_o
    float l[8];
    #pragma unroll
    for (int i = 0; i < 8; ++i) l[i] = __shfl(logit, i * 8);
    float m = l[0];
    #pragma unroll
    for (int i = 1; i < 8; ++i) m = fmaxf(m, l[i]);
    float p[8]; float sum = 0.f;
    #pragma unroll
    for (int i = 0; i < 8; ++i) { p[i] = expf(l[i] - m); sum += p[i]; }
    float inv = 1.f / sum;
    #pragma unroll
    for (int i = 0; i < 8; ++i) p[i] *= inv;
    // top-2 (ties -> smaller index, matching jax.lax.top_k)
    int i1 = 0; float v1 = p[0];
    #pragma unroll
    for (int i = 1; i < 8; ++i) if (p[i] > v1) { v1 = p[i]; i1 = i; }
    int i2 = -1; float v2 = -1.f;
    #pragma unroll
    for (int i = 0; i < 8; ++i) if (i != i1 && p[i] > v2) { v2 = p[i]; i2 = i; }
    if (lane < 8) {
        router_p[(size_t)b * 8 + lane] = p[lane];
        float g = (lane == i1) ? v1 * 0.5f : ((lane == i2) ? v2 * 0.5f : 0.f);
        gate[(size_t)b * 8 + lane] = g;   // includes /TOPK fold
    }
    if (blockIdx.x == 0 && threadIdx.x == 0) lb_out[0] = 0.f;
}

// ---------------- fused dense expert kernel: per block 32 rows, loop all 8 experts,
// 3 MFMA layers through LDS, gate-weighted accumulate, deterministic.
__global__ __launch_bounds__(512) void expert_fused_kernel(
    const float* __restrict__ x,
    const __hip_bfloat16* __restrict__ W1q,  // (8,512,768) ternary
    const __hip_bfloat16* __restrict__ W2q,  // (8,256,512)
    const __hip_bfloat16* __restrict__ W3q,  // (8,64,256) zero-padded rows 50..63
    const float* __restrict__ s1, const float* __restrict__ s2, const float* __restrict__ s3,
    const float* __restrict__ eb1, const float* __restrict__ eb2, const float* __restrict__ eb3,
    const float* __restrict__ gate,          // (16384,8), pre-divided by TOPK
    float* __restrict__ out)                 // (16384,50)
{
    __shared__ __align__(16) __hip_bfloat16 Xb[32][776];     // 768 + 8 pad
    __shared__ __align__(16) __hip_bfloat16 A1s[32][520];    // 512 + 8 pad
    __shared__ __align__(16) __hip_bfloat16 A2s[32][264];    // 256 + 8 pad
    __shared__ float Oacc[32][66];
    __shared__ float g_lds[32];

    const int tid = threadIdx.x;
    const int wave = tid >> 6;
    const int lane = tid & 63;
    const int lm = lane & 15;   // A row / B col within fragment
    const int lk = lane >> 4;   // k-octet
    const int r0 = blockIdx.x * 32;

    for (int i = tid; i < 32 * 66; i += 512) ((float*)Oacc)[i] = 0.f;

    // stage 32 rows of x as bf16
    for (int i = tid; i < 32 * (IN_DIM / 4); i += 512) {
        int row = i / (IN_DIM / 4), c4 = (i % (IN_DIM / 4)) * 4;
        float4 v = *(const float4*)&x[(size_t)(r0 + row) * IN_DIM + c4];
        Xb[row][c4 + 0] = __float2bfloat16(v.x);
        Xb[row][c4 + 1] = __float2bfloat16(v.y);
        Xb[row][c4 + 2] = __float2bfloat16(v.z);
        Xb[row][c4 + 3] = __float2bfloat16(v.w);
    }
    __syncthreads();

    for (int e = 0; e < NE; ++e) {
        if (tid < 32) g_lds[tid] = gate[(size_t)(r0 + tid) * NE + e];
        // ---- layer 1: Xb(32x768) @ W1q_e(512x768)^T -> A1s(32x512), scale+bias+relu
        {
            const __hip_bfloat16* W = W1q + (size_t)e * H1 * IN_DIM;
            const float* bias = eb1 + e * H1;
            const float sc = s1[e];
            f32x4 acc[2][4] = {};
            for (int kk = 0; kk < IN_DIM; kk += 32) {
                bf16x8 a0 = *(const bf16x8*)&Xb[lm][kk + lk * 8];
                bf16x8 a1 = *(const bf16x8*)&Xb[16 + lm][kk + lk * 8];
                #pragma unroll
                for (int n = 0; n < 4; ++n) {
                    int ncol = (wave * 4 + n) * 16 + lm;
                    bf16x8 b = *(const bf16x8*)&W[(size_t)ncol * IN_DIM + kk + lk * 8];
                    acc[0][n] = mfma16(a0, b, acc[0][n]);
                    acc[1][n] = mfma16(a1, b, acc[1][n]);
                }
            }
            #pragma unroll
            for (int n = 0; n < 4; ++n) {
                int ncol = (wave * 4 + n) * 16 + lm;
                float bv = bias[ncol];
                #pragma unroll
                for (int m = 0; m < 2; ++m)
                    #pragma unroll
                    for (int r = 0; r < 4; ++r) {
                        float v = fmaf(acc[m][n][r], sc, bv);
                        v = v > 0.f ? v : 0.f;
                        A1s[m * 16 + lk * 4 + r][ncol] = __float2bfloat16(v);
                    }
            }
        }
        __syncthreads();
        // ---- layer 2: A1s(32x512) @ W2q_e(256x512)^T -> A2s(32x256)
        {
            const __hip_bfloat16* W = W2q + (size_t)e * H2 * H1;
            const float* bias = eb2 + e * H2;
            const float sc = s2[e];
            f32x4 acc[2][2] = {};
            for (int kk = 0; kk < H1; kk += 32) {
                bf16x8 a0 = *(const bf16x8*)&A1s[lm][kk + lk * 8];
                bf16x8 a1 = *(const bf16x8*)&A1s[16 + lm][kk + lk * 8];
                #pragma unroll
                for (int n = 0; n < 2; ++n) {
                    int ncol = (wave * 2 + n) * 16 + lm;
                    bf16x8 b = *(const bf16x8*)&W[(size_t)ncol * H1 + kk + lk * 8];
                    acc[0][n] = mfma16(a0, b, acc[0][n]);
                    acc[1][n] = mfma16(a1, b, acc[1][n]);
                }
            }
            #pragma unroll
            for (int n = 0; n < 2; ++n) {
                int ncol = (wave * 2 + n) * 16 + lm;
                float bv = bias[ncol];
                #pragma unroll
                for (int m = 0; m < 2; ++m)
                    #pragma unroll
                    for (int r = 0; r < 4; ++r) {
                        float v = fmaf(acc[m][n][r], sc, bv);
                        v = v > 0.f ? v : 0.f;
                        A2s[m * 16 + lk * 4 + r][ncol] = __float2bfloat16(v);
                    }
            }
        }
        __syncthreads();
        // ---- layer 3: A2s(32x256) @ W3q_e(64x256)^T, gate-weighted accumulate into Oacc
        {
            const __hip_bfloat16* W = W3q + (size_t)e * NC_PAD * H2;
            const float* bias = eb3 + e * NC;
            const float sc = s3[e];
            const int mt = wave & 1, nt = wave >> 1;
            f32x4 acc = {};
            for (int kk = 0; kk < H2; kk += 32) {
                bf16x8 a = *(const bf16x8*)&A2s[mt * 16 + lm][kk + lk * 8];
                bf16x8 b = *(const bf16x8*)&W[(size_t)(nt * 16 + lm) * H2 + kk + lk * 8];
                acc = mfma16(a, b, acc);
            }
            int col = nt * 16 + lm;
            if (col < NC) {
                float bv = bias[col];
                #pragma unroll
                for (int r = 0; r < 4; ++r) {
                    int row = mt * 16 + lk * 4 + r;
                    float g = g_lds[row];
                    Oacc[row][col] += g * fmaf(acc[r], sc, bv);
                }
            }
        }
        __syncthreads();
    }
    for (int i = tid; i < 32 * NC; i += 512) {
        int row = i / NC, col = i % NC;
        out[(size_t)(r0 + row) * NC + col] = Oacc[row][col];
    }
}

extern "C" void kernel_launch(void* const* d_in, const int* in_sizes, int n_in,
                              void* d_out, int out_size, void* d_ws, size_t ws_size,
                              hipStream_t stream) {
    const float* x   = (const float*)d_in[0];
    const float* rW1 = (const float*)d_in[1];
    const float* rb1 = (const float*)d_in[2];
    const float* rW2 = (const float*)d_in[3];
    const float* rb2 = (const float*)d_in[4];
    const float* rW3 = (const float*)d_in[5];
    const float* rb3 = (const float*)d_in[6];
    const float* eW1 = (const float*)d_in[7];
    const float* eb1 = (const float*)d_in[8];
    const float* eW2 = (const float*)d_in[9];
    const float* eb2 = (const float*)d_in[10];
    const float* eW3 = (const float*)d_in[11];
    const float* eb3 = (const float*)d_in[12];

    float* out_main = (float*)d_out;                       // (16384,50)
    float* router_p = out_main + (size_t)B_ROWS * NC;      // (16384,8)
    float* lb_out   = router_p + (size_t)B_ROWS * NE;      // scalar

    char* ws = (char*)d_ws;
    size_t off = 0;
    __hip_bfloat16* W1q = (__hip_bfloat16*)(ws + off); off += (size_t)NE * H1 * IN_DIM * 2;   // 6291456
    __hip_bfloat16* W2q = (__hip_bfloat16*)(ws + off); off += (size_t)NE * H2 * H1 * 2;       // 2097152
    __hip_bfloat16* W3q = (__hip_bfloat16*)(ws + off); off += (size_t)NE * NC_PAD * H2 * 2;   // 262144
    float* h1   = (float*)(ws + off); off += (size_t)B_ROWS * RH1 * 4;                        // 16 MB
    float* h2   = (float*)(ws + off); off += (size_t)B_ROWS * RH2 * 4;                        // 8 MB
    float* gate = (float*)(ws + off); off += (size_t)B_ROWS * NE * 4;                         // 0.5 MB
    float* s1   = (float*)(ws + off); off += 64;
    float* s2   = (float*)(ws + off); off += 64;
    float* s3   = (float*)(ws + off); off += 64;

    // 1) ternarize expert weights (ternary bf16 + f32 scales)
    ternarize_kernel<<<NE, 512, 0, stream>>>(eW1, W1q, s1, H1, IN_DIM, H1);
    ternarize_kernel<<<NE, 512, 0, stream>>>(eW2, W2q, s2, H2, H1, H2);
    ternarize_kernel<<<NE, 512, 0, stream>>>(eW3, W3q, s3, NC, H2, NC_PAD);

    // 2) router (f32 exact path)
    gemm_nt_f32<1><<<dim3(B_ROWS / 64, RH1 / 64), 256, 0, stream>>>(x, rW1, rb1, h1, B_ROWS, RH1, IN_DIM);
    gemm_nt_f32<1><<<dim3(B_ROWS / 64, RH2 / 64), 256, 0, stream>>>(h1, rW2, rb2, h2, B_ROWS, RH2, RH1);
    router_head_kernel<<<B_ROWS / 4, 256, 0, stream>>>(h2, rW3, rb3, router_p, gate, lb_out);

    // 3) fused dense experts + gated combine
    expert_fused_kernel<<<B_ROWS / 32, 512, 0, stream>>>(
        x, W1q, W2q, W3q, s1, s2, s3, eb1, eb2, eb3, gate, out_main);
}